// Round 8
// baseline (664.872 us; speedup 1.0000x reference)
//
#include <hip/hip_runtime.h>
#include <math.h>
#include <stdint.h>

// ---------------------------------------------------------------------------
// B=4, L=2048, D=1024, H=16, Hd=64
// 1) wsplit_t: W_qkv -> W^T bf16 hi/lo
// 2) gemm_split<true,true>: qkv GEMM; epilogue writes Q (hi/lo, scaled) and
//    K / V^T as PRE-SWIZZLED tile images (attention stages them linearly).
// 3) attn_mfma: causal flash attn, bf16-split MFMA, double-buffered K/V
//    staging with counted vmcnt (loads in flight across barriers).
// 4) wsplit_t: W_lin -> W^T bf16 hi/lo (into dead Q region)
// 5) gemm_split<false,false>: out = ctx @ W_lin + b
//
// ws layout (128 MiB):
//   [0,96M)   Qh Ql Kh Kl Vth Vtl (16M each); after attn first 4M = Wlin^T
//   [96M,128M) pre-GEMM1: Wqkv^T hi/lo (12M); after attn: ctx hi/lo (16M+16M)
// ---------------------------------------------------------------------------

typedef __attribute__((ext_vector_type(8))) short bf16x8;
typedef __attribute__((ext_vector_type(4))) float f32x4;
typedef unsigned short u16;

#define MFMA16(a, b, c) __builtin_amdgcn_mfma_f32_16x16x32_bf16(a, b, c, 0, 0, 0)

// Split fp32 into bf16 hi + bf16 lo (x ~= hi + lo, residual ~2^-16 rel)
__device__ __forceinline__ void bsplit(float x, short& hi, short& lo) {
    unsigned u = __builtin_bit_cast(unsigned, x);
    unsigned hu = u & 0xffff0000u;
    hi = (short)(hu >> 16);
    float r = x - __builtin_bit_cast(float, hu);
    lo = (short)(__builtin_bit_cast(unsigned, r) >> 16);
}

// async global->LDS, 16B per lane
__device__ __forceinline__ void gload16(const void* g, void* l) {
    __builtin_amdgcn_global_load_lds(
        (const __attribute__((address_space(1))) void*)g,
        (__attribute__((address_space(3))) void*)l, 16, 0, 0);
}

// XOR swizzle for 64x64 bf16 tiles (short-index bits 3-5 ^= row&7).
__device__ __forceinline__ int swz(int row, int col) {
    return ((row << 6) | col) ^ ((row & 7) << 3);
}

// ---------------------------------------------------------------------------
// Transpose + split: W[K][N] f32 -> outh/outl[N][K] bf16
// ---------------------------------------------------------------------------
__global__ __launch_bounds__(256) void wsplit_t(
    const float* __restrict__ W, u16* __restrict__ outh, u16* __restrict__ outl,
    int K, int N)
{
    __shared__ float t[64][68];
    const int n0 = blockIdx.x * 64, k0 = blockIdx.y * 64;
    const int tid = threadIdx.x;
    const int r = tid >> 4, c4 = (tid & 15) * 4;
    #pragma unroll
    for (int i = 0; i < 4; ++i) {
        const int rr = r + i * 16;
        float4 v = *(const float4*)&W[(size_t)(k0 + rr) * N + n0 + c4];
        t[rr][c4 + 0] = v.x; t[rr][c4 + 1] = v.y;
        t[rr][c4 + 2] = v.z; t[rr][c4 + 3] = v.w;
    }
    __syncthreads();
    #pragma unroll
    for (int i = 0; i < 4; ++i) {
        const int nr = r + i * 16;
        unsigned h01 = 0, h23 = 0, l01 = 0, l23 = 0;
        {
            short hh, ll;
            bsplit(t[c4 + 0][nr], hh, ll); h01 |= (unsigned)(u16)hh; l01 |= (unsigned)(u16)ll;
            bsplit(t[c4 + 1][nr], hh, ll); h01 |= (unsigned)(u16)hh << 16; l01 |= (unsigned)(u16)ll << 16;
            bsplit(t[c4 + 2][nr], hh, ll); h23 |= (unsigned)(u16)hh; l23 |= (unsigned)(u16)ll;
            bsplit(t[c4 + 3][nr], hh, ll); h23 |= (unsigned)(u16)hh << 16; l23 |= (unsigned)(u16)ll << 16;
        }
        *(uint2*)&outh[(size_t)(n0 + nr) * K + k0 + c4] = make_uint2(h01, h23);
        *(uint2*)&outl[(size_t)(n0 + nr) * K + k0 + c4] = make_uint2(l01, l23);
    }
}

// ---------------------------------------------------------------------------
// bf16-split MFMA GEMM. 128x128 tile, BK=32, 4 waves (2x2 of 64x64).
// ---------------------------------------------------------------------------
template<bool AF32, bool QKVOUT>
__global__ __launch_bounds__(256) void gemm_split(
    const float* __restrict__ Af,
    const u16* __restrict__ Ah, const u16* __restrict__ Al,
    const u16* __restrict__ Bth, const u16* __restrict__ Btl,
    const float* __restrict__ bias, float* __restrict__ C,
    u16* __restrict__ qh, u16* __restrict__ ql,
    u16* __restrict__ kh, u16* __restrict__ kl,
    u16* __restrict__ vth, u16* __restrict__ vtl,
    int M, int N, int K)
{
    __shared__ u16 sAh[128 * 32], sAl[128 * 32], sBh[128 * 32], sBl[128 * 32];

    const int tid  = threadIdx.x;
    const int lane = tid & 63;
    const int ln   = lane & 15;
    const int lg   = lane >> 4;
    const int w    = tid >> 6;
    const int wr   = (w >> 1) * 64;
    const int wc   = (w & 1) * 64;
    const int row0 = blockIdx.y * 128;
    const int col0 = blockIdx.x * 128;

    f32x4 acc[4][4];
    #pragma unroll
    for (int mi = 0; mi < 4; ++mi)
        #pragma unroll
        for (int ni = 0; ni < 4; ++ni)
            acc[mi][ni] = (f32x4){0.f, 0.f, 0.f, 0.f};

    for (int kt = 0; kt < K; kt += 32) {
        __syncthreads();
        #pragma unroll
        for (int rd = 0; rd < 2; ++rd) {
            const int ch = tid + rd * 256;
            const int r = ch >> 2, kc = (ch & 3) * 8;
            gload16(Bth + (size_t)(col0 + r) * K + kt + kc, &sBh[ch * 8]);
            gload16(Btl + (size_t)(col0 + r) * K + kt + kc, &sBl[ch * 8]);
            if constexpr (!AF32) {
                gload16(Ah + (size_t)(row0 + r) * K + kt + kc, &sAh[ch * 8]);
                gload16(Al + (size_t)(row0 + r) * K + kt + kc, &sAl[ch * 8]);
            }
        }
        if constexpr (AF32) {
            const int r = tid >> 1, ks = (tid & 1) * 16;
            const float* ap = Af + (size_t)(row0 + r) * K + kt + ks;
            float v[16];
            *(float4*)&v[0]  = *(const float4*)(ap + 0);
            *(float4*)&v[4]  = *(const float4*)(ap + 4);
            *(float4*)&v[8]  = *(const float4*)(ap + 8);
            *(float4*)&v[12] = *(const float4*)(ap + 12);
            bf16x8 h0, h1, l0, l1;
            #pragma unroll
            for (int e = 0; e < 8; ++e) {
                short hh, ll;
                bsplit(v[e], hh, ll);     h0[e] = hh; l0[e] = ll;
                bsplit(v[8 + e], hh, ll); h1[e] = hh; l1[e] = ll;
            }
            *(bf16x8*)&sAh[r * 32 + ks]     = h0;
            *(bf16x8*)&sAh[r * 32 + ks + 8] = h1;
            *(bf16x8*)&sAl[r * 32 + ks]     = l0;
            *(bf16x8*)&sAl[r * 32 + ks + 8] = l1;
        }
        __syncthreads();

        bf16x8 a_h[4], a_l[4], b_h[4], b_l[4];
        #pragma unroll
        for (int mi = 0; mi < 4; ++mi) {
            const int o = (wr + mi * 16 + ln) * 32 + lg * 8;
            a_h[mi] = *(const bf16x8*)&sAh[o];
            a_l[mi] = *(const bf16x8*)&sAl[o];
        }
        #pragma unroll
        for (int ni = 0; ni < 4; ++ni) {
            const int o = (wc + ni * 16 + ln) * 32 + lg * 8;
            b_h[ni] = *(const bf16x8*)&sBh[o];
            b_l[ni] = *(const bf16x8*)&sBl[o];
        }
        #pragma unroll
        for (int mi = 0; mi < 4; ++mi)
            #pragma unroll
            for (int ni = 0; ni < 4; ++ni) {
                acc[mi][ni] = MFMA16(a_h[mi], b_h[ni], acc[mi][ni]);
                acc[mi][ni] = MFMA16(a_l[mi], b_h[ni], acc[mi][ni]);
                acc[mi][ni] = MFMA16(a_h[mi], b_l[ni], acc[mi][ni]);
            }
    }

    if constexpr (QKVOUT) {
        const int t = col0 >> 10;             // 0=q 1=k 2=v, block-uniform
        #pragma unroll
        for (int ni = 0; ni < 4; ++ni) {
            const int col = col0 + wc + ni * 16 + ln;
            const int hh  = (col & 1023) >> 6;
            const int d   = col & 63;
            const float bi = bias[col];
            const size_t hb = (size_t)((row0 >> 11) * 16 + hh);   // batch*16+head
            #pragma unroll
            for (int mi = 0; mi < 4; ++mi) {
                const int l0g = (row0 + wr + mi * 16 + lg * 4) & 2047;
                if (t == 0) {
                    #pragma unroll
                    for (int j = 0; j < 4; ++j) {
                        short hi_, lo_;
                        bsplit((acc[mi][ni][j] + bi) * 0.125f, hi_, lo_);
                        const size_t p = (hb * 2048 + l0g + j) * 64 + d;
                        qh[p] = (u16)hi_; ql[p] = (u16)lo_;
                    }
                } else if (t == 1) {
                    #pragma unroll
                    for (int j = 0; j < 4; ++j) {
                        short hi_, lo_;
                        bsplit(acc[mi][ni][j] + bi, hi_, lo_);
                        const int l = l0g + j;
                        const size_t p = (hb * 32 + (l >> 6)) * 4096 + swz(l & 63, d);
                        kh[p] = (u16)hi_; kl[p] = (u16)lo_;
                    }
                } else {
                    unsigned h01 = 0, h23 = 0, l01 = 0, l23 = 0;
                    #pragma unroll
                    for (int j = 0; j < 4; ++j) {
                        short hi_, lo_;
                        bsplit(acc[mi][ni][j] + bi, hi_, lo_);
                        if (j < 2) {
                            h01 |= (unsigned)(u16)hi_ << (16 * j);
                            l01 |= (unsigned)(u16)lo_ << (16 * j);
                        } else {
                            h23 |= (unsigned)(u16)hi_ << (16 * (j - 2));
                            l23 |= (unsigned)(u16)lo_ << (16 * (j - 2));
                        }
                    }
                    const size_t p = (hb * 32 + (l0g >> 6)) * 4096 + swz(d, l0g & 63);
                    *(uint2*)&vth[p] = make_uint2(h01, h23);
                    *(uint2*)&vtl[p] = make_uint2(l01, l23);
                }
            }
        }
    } else {
        #pragma unroll
        for (int ni = 0; ni < 4; ++ni) {
            const int col = col0 + wc + ni * 16 + ln;
            const float bi = bias[col];
            #pragma unroll
            for (int mi = 0; mi < 4; ++mi)
                #pragma unroll
                for (int j = 0; j < 4; ++j) {
                    const int row = row0 + wr + mi * 16 + lg * 4 + j;
                    C[(size_t)row * N + col] = acc[mi][ni][j] + bi;
                }
        }
    }
}

// ---------------------------------------------------------------------------
// Flash attention, bf16-split MFMA. K/V pre-split + pre-swizzled in global.
// NEW: double-buffered staging with counted vmcnt — next tile's 8
// global_load_lds stay in flight across the barrier (never drain to 0
// mid-loop); raw s_barrier, no __syncthreads.
// ---------------------------------------------------------------------------
__global__ __launch_bounds__(256) void attn_mfma(
    const u16* __restrict__ Qh, const u16* __restrict__ Ql,
    const u16* __restrict__ Kh, const u16* __restrict__ Kl,
    const u16* __restrict__ Vth, const u16* __restrict__ Vtl,
    u16* __restrict__ ctxh, u16* __restrict__ ctxl)
{
    const int L = 2048, D = 1024;
    const int qt = blockIdx.x;
    const int h  = blockIdx.y;
    const int b  = blockIdx.z;
    const int q0 = qt * 64;

    __shared__ u16 sKh[2][4096], sKl[2][4096], sVh[2][4096], sVl[2][4096]; // 64K
    __shared__ u16 P_hi[4096], P_lo[4096];                                 // 16K

    const int tid = threadIdx.x;
    const int w = tid >> 6;
    const int lane = tid & 63;
    const int ln = lane & 15;
    const int lg = lane >> 4;
    const size_t hb = (size_t)(b * 16 + h);

    // Q fragments (scale+bias folded by GEMM1 epilogue)
    bf16x8 qa_hi[2], qa_lo[2];
    {
        const size_t qoff = (hb * 2048 + q0 + w * 16 + ln) * 64 + lg * 8;
        qa_hi[0] = *(const bf16x8*)(Qh + qoff);
        qa_hi[1] = *(const bf16x8*)(Qh + qoff + 32);
        qa_lo[0] = *(const bf16x8*)(Ql + qoff);
        qa_lo[1] = *(const bf16x8*)(Ql + qoff + 32);
    }

    const int c0 = tid * 8, c1 = (tid + 256) * 8;
    auto stage = [&](int buf, int kt) {
        const size_t tb = (hb * 32 + kt) * 4096;
        gload16(Kh  + tb + c0, &sKh[buf][c0]);
        gload16(Kh  + tb + c1, &sKh[buf][c1]);
        gload16(Kl  + tb + c0, &sKl[buf][c0]);
        gload16(Kl  + tb + c1, &sKl[buf][c1]);
        gload16(Vth + tb + c0, &sVh[buf][c0]);
        gload16(Vth + tb + c1, &sVh[buf][c1]);
        gload16(Vtl + tb + c0, &sVl[buf][c0]);
        gload16(Vtl + tb + c1, &sVl[buf][c1]);
    };

    float m[4], lsum[4];
    f32x4 acc[4];
    #pragma unroll
    for (int r = 0; r < 4; ++r) { m[r] = -INFINITY; lsum[r] = 0.f; }
    #pragma unroll
    for (int n = 0; n < 4; ++n) acc[n] = (f32x4){0.f, 0.f, 0.f, 0.f};

    stage(0, 0);   // prologue prefetch

    for (int kt = 0; kt <= qt; ++kt) {
        const int cur = kt & 1;
        // Issue next tile's loads BEFORE waiting on current tile's. Counted
        // vmcnt(8): waits for current buf's 8 loads, leaves next 8 in flight.
        if (kt < qt) {
            stage(cur ^ 1, kt + 1);
            asm volatile("s_waitcnt vmcnt(8)" ::: "memory");
        } else {
            asm volatile("s_waitcnt vmcnt(0)" ::: "memory");
        }
        __builtin_amdgcn_sched_barrier(0);
        __builtin_amdgcn_s_barrier();     // all waves: buf[cur] image complete
        asm volatile("" ::: "memory");

        // S = Q K^T
        f32x4 s[4];
        #pragma unroll
        for (int n = 0; n < 4; ++n) {
            f32x4 sa = (f32x4){0.f, 0.f, 0.f, 0.f};
            #pragma unroll
            for (int ks = 0; ks < 2; ++ks) {
                bf16x8 kb_hi = *(const bf16x8*)&sKh[cur][swz(n * 16 + ln, ks * 32 + lg * 8)];
                bf16x8 kb_lo = *(const bf16x8*)&sKl[cur][swz(n * 16 + ln, ks * 32 + lg * 8)];
                sa = MFMA16(qa_hi[ks], kb_hi, sa);
                sa = MFMA16(qa_lo[ks], kb_hi, sa);
                sa = MFMA16(qa_hi[ks], kb_lo, sa);
            }
            s[n] = sa;
        }

        if (kt == qt) {    // causal mask on the diagonal tile
            #pragma unroll
            for (int n = 0; n < 4; ++n)
                #pragma unroll
                for (int r = 0; r < 4; ++r) {
                    const int key = n * 16 + ln;
                    const int qr  = w * 16 + lg * 4 + r;
                    if (key > qr) s[n][r] = -INFINITY;
                }
        }

        // Online softmax (row stats across the 16 lanes sharing lg)
        float al[4];
        #pragma unroll
        for (int r = 0; r < 4; ++r) {
            float t = fmaxf(fmaxf(s[0][r], s[1][r]), fmaxf(s[2][r], s[3][r]));
            t = fmaxf(t, __shfl_xor(t, 1));
            t = fmaxf(t, __shfl_xor(t, 2));
            t = fmaxf(t, __shfl_xor(t, 4));
            t = fmaxf(t, __shfl_xor(t, 8));
            const float mn = fmaxf(m[r], t);
            al[r] = __expf(m[r] - mn);
            m[r] = mn;
        }

        float ps[4] = {0.f, 0.f, 0.f, 0.f};
        #pragma unroll
        for (int n = 0; n < 4; ++n) {
            #pragma unroll
            for (int r = 0; r < 4; ++r) {
                const float p = __expf(s[n][r] - m[r]);
                ps[r] += p;
                short ph, pl;
                bsplit(p, ph, pl);
                const int row = w * 16 + lg * 4 + r;
                const int key = n * 16 + ln;
                P_hi[swz(row, key)] = (u16)ph;
                P_lo[swz(row, key)] = (u16)pl;
            }
        }
        #pragma unroll
        for (int r = 0; r < 4; ++r) {
            float t = ps[r];
            t += __shfl_xor(t, 1);
            t += __shfl_xor(t, 2);
            t += __shfl_xor(t, 4);
            t += __shfl_xor(t, 8);
            lsum[r] = lsum[r] * al[r] + t;
            acc[0][r] *= al[r];
            acc[1][r] *= al[r];
            acc[2][r] *= al[r];
            acc[3][r] *= al[r];
        }

        // PV (P round-trip is wave-local; same-wave LDS ordering suffices)
        bf16x8 pa_hi[2], pa_lo[2];
        #pragma unroll
        for (int ks = 0; ks < 2; ++ks) {
            pa_hi[ks] = *(const bf16x8*)&P_hi[swz(w * 16 + ln, ks * 32 + lg * 8)];
            pa_lo[ks] = *(const bf16x8*)&P_lo[swz(w * 16 + ln, ks * 32 + lg * 8)];
        }
        #pragma unroll
        for (int n = 0; n < 4; ++n) {
            #pragma unroll
            for (int ks = 0; ks < 2; ++ks) {
                bf16x8 vb_hi = *(const bf16x8*)&sVh[cur][swz(n * 16 + ln, ks * 32 + lg * 8)];
                bf16x8 vb_lo = *(const bf16x8*)&sVl[cur][swz(n * 16 + ln, ks * 32 + lg * 8)];
                acc[n] = MFMA16(pa_hi[ks], vb_hi, acc[n]);
                acc[n] = MFMA16(pa_lo[ks], vb_hi, acc[n]);
                acc[n] = MFMA16(pa_hi[ks], vb_lo, acc[n]);
            }
        }

        asm volatile("" ::: "memory");
        __builtin_amdgcn_s_barrier();     // all waves done reading buf[cur]
    }

    #pragma unroll
    for (int r = 0; r < 4; ++r) {
        const float inv = 1.f / lsum[r];
        const int q = q0 + w * 16 + lg * 4 + r;
        const size_t idx = ((size_t)(b * L) + q) * D + h * 64;
        #pragma unroll
        for (int n = 0; n < 4; ++n) {
            short hh, ll;
            bsplit(acc[n][r] * inv, hh, ll);
            ctxh[idx + n * 16 + ln] = (u16)hh;
            ctxl[idx + n * 16 + ln] = (u16)ll;
        }
    }
}

extern "C" void kernel_launch(void* const* d_in, const int* in_sizes, int n_in,
                              void* d_out, int out_size, void* d_ws, size_t ws_size,
                              hipStream_t stream) {
    const float* x     = (const float*)d_in[0];
    const float* W_qkv = (const float*)d_in[1];
    const float* b_qkv = (const float*)d_in[2];
    const float* W_lin = (const float*)d_in[3];
    const float* b_lin = (const float*)d_in[4];
    float* out = (float*)d_out;

    const int M = 8192, D = 1024, D3 = 3072;
    const size_t MB = 1024 * 1024;

    char* ws = (char*)d_ws;
    u16* Qh  = (u16*)(ws + 0 * MB);
    u16* Ql  = (u16*)(ws + 16 * MB);
    u16* Kh  = (u16*)(ws + 32 * MB);
    u16* Kl  = (u16*)(ws + 48 * MB);
    u16* Vth = (u16*)(ws + 64 * MB);
    u16* Vtl = (u16*)(ws + 80 * MB);
    u16* wqh = (u16*)(ws + 96 * MB);    // pre-attn only (6M)
    u16* wql = (u16*)(ws + 102 * MB);   // pre-attn only (6M)
    u16* ctxh = (u16*)(ws + 96 * MB);   // post-attn (16M)
    u16* ctxl = (u16*)(ws + 112 * MB);  // post-attn (16M)
    u16* wlh = (u16*)(ws + 0 * MB);     // post-attn (2M, dead Q region)
    u16* wll = (u16*)(ws + 2 * MB);     // post-attn (2M)

    // 1) W_qkv -> transposed split
    wsplit_t<<<dim3(D3 / 64, D / 64), 256, 0, stream>>>(W_qkv, wqh, wql, D, D3);
    // 2) QKV GEMM, epilogue -> attention-ready Q/K/V^T layouts
    gemm_split<true, true><<<dim3(D3 / 128, M / 128), 256, 0, stream>>>(
        x, nullptr, nullptr, wqh, wql, b_qkv, nullptr,
        Qh, Ql, Kh, Kl, Vth, Vtl, M, D3, D);
    // 3) attention -> ctx hi/lo (clobbers wq region: dead)
    attn_mfma<<<dim3(32, 16, 4), 256, 0, stream>>>(
        Qh, Ql, Kh, Kl, Vth, Vtl, ctxh, ctxl);
    // 4) W_lin -> transposed split (into dead Q region)
    wsplit_t<<<dim3(D / 64, D / 64), 256, 0, stream>>>(W_lin, wlh, wll, D, D);
    // 5) out = ctx @ W_lin + b_lin
    gemm_split<false, false><<<dim3(D / 128, M / 128), 256, 0, stream>>>(
        nullptr, ctxh, ctxl, wlh, wll, b_lin, out,
        nullptr, nullptr, nullptr, nullptr, nullptr, nullptr, M, D, D);
}

// Round 9
// 529.674 us; speedup vs baseline: 1.2552x; 1.2552x over previous
//
#include <hip/hip_runtime.h>
#include <math.h>
#include <stdint.h>

// ---------------------------------------------------------------------------
// B=4, L=2048, D=1024, H=16, Hd=64
// 1) wsplit_t: W_qkv -> W^T bf16 hi/lo
// 2) gemm_split<true,true>: qkv GEMM; epilogue writes Q (hi/lo, scaled), K as
//    swizzled tile image, V^T as PI-PERMUTED swizzled tile image (k-slot
//    order matching PV's B-fragment so P never leaves registers).
// 3) attn_mfma: causal flash attn, swapped-operand MFMA, in-register softmax.
// 4) wsplit_t: W_lin -> W^T bf16 hi/lo (into dead Q region)
// 5) gemm_split<false,false>: out = ctx @ W_lin + b
//
// ws layout (128 MiB):
//   [0,96M)   Qh Ql Kh Kl Vth Vtl (16M each); after attn first 4M = Wlin^T
//   [96M,128M) pre-GEMM1: Wqkv^T hi/lo (12M); after attn: ctx hi/lo (16M+16M)
// ---------------------------------------------------------------------------

typedef __attribute__((ext_vector_type(8))) short bf16x8;
typedef __attribute__((ext_vector_type(4))) float f32x4;
typedef unsigned short u16;

#define MFMA16(a, b, c) __builtin_amdgcn_mfma_f32_16x16x32_bf16(a, b, c, 0, 0, 0)

// Split fp32 into bf16 hi + bf16 lo (x ~= hi + lo, residual ~2^-16 rel)
__device__ __forceinline__ void bsplit(float x, short& hi, short& lo) {
    unsigned u = __builtin_bit_cast(unsigned, x);
    unsigned hu = u & 0xffff0000u;
    hi = (short)(hu >> 16);
    float r = x - __builtin_bit_cast(float, hu);
    lo = (short)(__builtin_bit_cast(unsigned, r) >> 16);
}

// async global->LDS, 16B per lane
__device__ __forceinline__ void gload16(const void* g, void* l) {
    __builtin_amdgcn_global_load_lds(
        (const __attribute__((address_space(1))) void*)g,
        (__attribute__((address_space(3))) void*)l, 16, 0, 0);
}

// XOR swizzle for 64x64 bf16 tiles (short-index bits 3-5 ^= row&7).
__device__ __forceinline__ int swz(int row, int col) {
    return ((row << 6) | col) ^ ((row & 7) << 3);
}

// PV k-slot permutation: slot s=(ks*32+lg*8+e) carries key pi(s) =
// 16*(2ks+(e>>2)) + 4lg + (e&3). V image stores VT[d][pi(s)] at col s, so
// sigma = pi^-1: key kk -> slot (kk&32) | ((kk&12)<<1) | ((kk&16)>>2) | (kk&3).
__device__ __forceinline__ int vslot(int kk) {
    return (kk & 32) | ((kk & 12) << 1) | ((kk & 16) >> 2) | (kk & 3);
}

// ---------------------------------------------------------------------------
// Transpose + split: W[K][N] f32 -> outh/outl[N][K] bf16
// ---------------------------------------------------------------------------
__global__ __launch_bounds__(256) void wsplit_t(
    const float* __restrict__ W, u16* __restrict__ outh, u16* __restrict__ outl,
    int K, int N)
{
    __shared__ float t[64][68];
    const int n0 = blockIdx.x * 64, k0 = blockIdx.y * 64;
    const int tid = threadIdx.x;
    const int r = tid >> 4, c4 = (tid & 15) * 4;
    #pragma unroll
    for (int i = 0; i < 4; ++i) {
        const int rr = r + i * 16;
        float4 v = *(const float4*)&W[(size_t)(k0 + rr) * N + n0 + c4];
        t[rr][c4 + 0] = v.x; t[rr][c4 + 1] = v.y;
        t[rr][c4 + 2] = v.z; t[rr][c4 + 3] = v.w;
    }
    __syncthreads();
    #pragma unroll
    for (int i = 0; i < 4; ++i) {
        const int nr = r + i * 16;
        unsigned h01 = 0, h23 = 0, l01 = 0, l23 = 0;
        {
            short hh, ll;
            bsplit(t[c4 + 0][nr], hh, ll); h01 |= (unsigned)(u16)hh; l01 |= (unsigned)(u16)ll;
            bsplit(t[c4 + 1][nr], hh, ll); h01 |= (unsigned)(u16)hh << 16; l01 |= (unsigned)(u16)ll << 16;
            bsplit(t[c4 + 2][nr], hh, ll); h23 |= (unsigned)(u16)hh; l23 |= (unsigned)(u16)ll;
            bsplit(t[c4 + 3][nr], hh, ll); h23 |= (unsigned)(u16)hh << 16; l23 |= (unsigned)(u16)ll << 16;
        }
        *(uint2*)&outh[(size_t)(n0 + nr) * K + k0 + c4] = make_uint2(h01, h23);
        *(uint2*)&outl[(size_t)(n0 + nr) * K + k0 + c4] = make_uint2(l01, l23);
    }
}

// ---------------------------------------------------------------------------
// bf16-split MFMA GEMM. 128x128 tile, BK=32, 4 waves (2x2 of 64x64).
// ---------------------------------------------------------------------------
template<bool AF32, bool QKVOUT>
__global__ __launch_bounds__(256) void gemm_split(
    const float* __restrict__ Af,
    const u16* __restrict__ Ah, const u16* __restrict__ Al,
    const u16* __restrict__ Bth, const u16* __restrict__ Btl,
    const float* __restrict__ bias, float* __restrict__ C,
    u16* __restrict__ qh, u16* __restrict__ ql,
    u16* __restrict__ kh, u16* __restrict__ kl,
    u16* __restrict__ vth, u16* __restrict__ vtl,
    int M, int N, int K)
{
    __shared__ u16 sAh[128 * 32], sAl[128 * 32], sBh[128 * 32], sBl[128 * 32];

    const int tid  = threadIdx.x;
    const int lane = tid & 63;
    const int ln   = lane & 15;
    const int lg   = lane >> 4;
    const int w    = tid >> 6;
    const int wr   = (w >> 1) * 64;
    const int wc   = (w & 1) * 64;
    const int row0 = blockIdx.y * 128;
    const int col0 = blockIdx.x * 128;

    f32x4 acc[4][4];
    #pragma unroll
    for (int mi = 0; mi < 4; ++mi)
        #pragma unroll
        for (int ni = 0; ni < 4; ++ni)
            acc[mi][ni] = (f32x4){0.f, 0.f, 0.f, 0.f};

    for (int kt = 0; kt < K; kt += 32) {
        __syncthreads();
        #pragma unroll
        for (int rd = 0; rd < 2; ++rd) {
            const int ch = tid + rd * 256;
            const int r = ch >> 2, kc = (ch & 3) * 8;
            gload16(Bth + (size_t)(col0 + r) * K + kt + kc, &sBh[ch * 8]);
            gload16(Btl + (size_t)(col0 + r) * K + kt + kc, &sBl[ch * 8]);
            if constexpr (!AF32) {
                gload16(Ah + (size_t)(row0 + r) * K + kt + kc, &sAh[ch * 8]);
                gload16(Al + (size_t)(row0 + r) * K + kt + kc, &sAl[ch * 8]);
            }
        }
        if constexpr (AF32) {
            const int r = tid >> 1, ks = (tid & 1) * 16;
            const float* ap = Af + (size_t)(row0 + r) * K + kt + ks;
            float v[16];
            *(float4*)&v[0]  = *(const float4*)(ap + 0);
            *(float4*)&v[4]  = *(const float4*)(ap + 4);
            *(float4*)&v[8]  = *(const float4*)(ap + 8);
            *(float4*)&v[12] = *(const float4*)(ap + 12);
            bf16x8 h0, h1, l0, l1;
            #pragma unroll
            for (int e = 0; e < 8; ++e) {
                short hh, ll;
                bsplit(v[e], hh, ll);     h0[e] = hh; l0[e] = ll;
                bsplit(v[8 + e], hh, ll); h1[e] = hh; l1[e] = ll;
            }
            *(bf16x8*)&sAh[r * 32 + ks]     = h0;
            *(bf16x8*)&sAh[r * 32 + ks + 8] = h1;
            *(bf16x8*)&sAl[r * 32 + ks]     = l0;
            *(bf16x8*)&sAl[r * 32 + ks + 8] = l1;
        }
        __syncthreads();

        bf16x8 a_h[4], a_l[4], b_h[4], b_l[4];
        #pragma unroll
        for (int mi = 0; mi < 4; ++mi) {
            const int o = (wr + mi * 16 + ln) * 32 + lg * 8;
            a_h[mi] = *(const bf16x8*)&sAh[o];
            a_l[mi] = *(const bf16x8*)&sAl[o];
        }
        #pragma unroll
        for (int ni = 0; ni < 4; ++ni) {
            const int o = (wc + ni * 16 + ln) * 32 + lg * 8;
            b_h[ni] = *(const bf16x8*)&sBh[o];
            b_l[ni] = *(const bf16x8*)&sBl[o];
        }
        #pragma unroll
        for (int mi = 0; mi < 4; ++mi)
            #pragma unroll
            for (int ni = 0; ni < 4; ++ni) {
                acc[mi][ni] = MFMA16(a_h[mi], b_h[ni], acc[mi][ni]);
                acc[mi][ni] = MFMA16(a_l[mi], b_h[ni], acc[mi][ni]);
                acc[mi][ni] = MFMA16(a_h[mi], b_l[ni], acc[mi][ni]);
            }
    }

    if constexpr (QKVOUT) {
        const int t = col0 >> 10;             // 0=q 1=k 2=v, block-uniform
        #pragma unroll
        for (int ni = 0; ni < 4; ++ni) {
            const int col = col0 + wc + ni * 16 + ln;
            const int hh  = (col & 1023) >> 6;
            const int d   = col & 63;
            const float bi = bias[col];
            const size_t hb = (size_t)((row0 >> 11) * 16 + hh);   // batch*16+head
            #pragma unroll
            for (int mi = 0; mi < 4; ++mi) {
                const int l0g = (row0 + wr + mi * 16 + lg * 4) & 2047;
                if (t == 0) {
                    #pragma unroll
                    for (int j = 0; j < 4; ++j) {
                        short hi_, lo_;
                        bsplit((acc[mi][ni][j] + bi) * 0.125f, hi_, lo_);
                        const size_t p = (hb * 2048 + l0g + j) * 64 + d;
                        qh[p] = (u16)hi_; ql[p] = (u16)lo_;
                    }
                } else if (t == 1) {
                    #pragma unroll
                    for (int j = 0; j < 4; ++j) {
                        short hi_, lo_;
                        bsplit(acc[mi][ni][j] + bi, hi_, lo_);
                        const int l = l0g + j;
                        const size_t p = (hb * 32 + (l >> 6)) * 4096 + swz(l & 63, d);
                        kh[p] = (u16)hi_; kl[p] = (u16)lo_;
                    }
                } else {
                    // V^T image in pi-permuted slot order; 4 consecutive keys
                    // (kk 4-aligned) stay 4-consecutive slots -> one 8B store.
                    unsigned h01 = 0, h23 = 0, l01 = 0, l23 = 0;
                    #pragma unroll
                    for (int j = 0; j < 4; ++j) {
                        short hi_, lo_;
                        bsplit(acc[mi][ni][j] + bi, hi_, lo_);
                        if (j < 2) {
                            h01 |= (unsigned)(u16)hi_ << (16 * j);
                            l01 |= (unsigned)(u16)lo_ << (16 * j);
                        } else {
                            h23 |= (unsigned)(u16)hi_ << (16 * (j - 2));
                            l23 |= (unsigned)(u16)lo_ << (16 * (j - 2));
                        }
                    }
                    const int s0 = vslot(l0g & 63);
                    const size_t p = (hb * 32 + (l0g >> 6)) * 4096 + swz(d, s0);
                    *(uint2*)&vth[p] = make_uint2(h01, h23);
                    *(uint2*)&vtl[p] = make_uint2(l01, l23);
                }
            }
        }
    } else {
        #pragma unroll
        for (int ni = 0; ni < 4; ++ni) {
            const int col = col0 + wc + ni * 16 + ln;
            const float bi = bias[col];
            #pragma unroll
            for (int mi = 0; mi < 4; ++mi)
                #pragma unroll
                for (int j = 0; j < 4; ++j) {
                    const int row = row0 + wr + mi * 16 + lg * 4 + j;
                    C[(size_t)row * N + col] = acc[mi][ni][j] + bi;
                }
        }
    }
}

// ---------------------------------------------------------------------------
// Flash attention, swapped-operand bf16-split MFMA, in-register softmax.
// S^T = MFMA(K, Q): lane (ln,lg) holds q = q0+w*16+ln, keys {n*16+lg*4+r}.
// Softmax: 15-op local tree + 2 shfl_xor (one chain). P feeds PV's B-frag
// directly via the pi slot permutation (register packing only).
// PV: O^T = MFMA(V^T-image, P^T); acc[n][r] = O[q][d=n*16+lg*4+r].
// ---------------------------------------------------------------------------
__global__ __launch_bounds__(256) void attn_mfma(
    const u16* __restrict__ Qh, const u16* __restrict__ Ql,
    const u16* __restrict__ Kh, const u16* __restrict__ Kl,
    const u16* __restrict__ Vth, const u16* __restrict__ Vtl,
    u16* __restrict__ ctxh, u16* __restrict__ ctxl)
{
    const int L = 2048, D = 1024;
    const int qt = blockIdx.x;
    const int h  = blockIdx.y;
    const int b  = blockIdx.z;
    const int q0 = qt * 64;

    __shared__ u16 sKh[4096], sKl[4096], sVh[4096], sVl[4096];   // 32 KiB

    const int tid = threadIdx.x;
    const int w = tid >> 6;
    const int lane = tid & 63;
    const int ln = lane & 15;
    const int lg = lane >> 4;
    const size_t hb = (size_t)(b * 16 + h);

    // Q fragments (scale+bias folded by GEMM1); used as MFMA B operand.
    bf16x8 qb_hi[2], qb_lo[2];
    {
        const size_t qoff = (hb * 2048 + q0 + w * 16 + ln) * 64 + lg * 8;
        qb_hi[0] = *(const bf16x8*)(Qh + qoff);
        qb_hi[1] = *(const bf16x8*)(Qh + qoff + 32);
        qb_lo[0] = *(const bf16x8*)(Ql + qoff);
        qb_lo[1] = *(const bf16x8*)(Ql + qoff + 32);
    }

    float m = -INFINITY, lsum = 0.f;
    f32x4 acc[4];
    #pragma unroll
    for (int n = 0; n < 4; ++n) acc[n] = (f32x4){0.f, 0.f, 0.f, 0.f};

    const int c0 = tid * 8, c1 = (tid + 256) * 8;

    for (int kt = 0; kt <= qt; ++kt) {
        __syncthreads();   // previous tile's K/V reads done before overwrite
        {
            const size_t tb = (hb * 32 + kt) * 4096;
            gload16(Kh  + tb + c0, &sKh[c0]);
            gload16(Kh  + tb + c1, &sKh[c1]);
            gload16(Kl  + tb + c0, &sKl[c0]);
            gload16(Kl  + tb + c1, &sKl[c1]);
            gload16(Vth + tb + c0, &sVh[c0]);
            gload16(Vth + tb + c1, &sVh[c1]);
            gload16(Vtl + tb + c0, &sVl[c0]);
            gload16(Vtl + tb + c1, &sVl[c1]);
        }
        __syncthreads();   // drains vmcnt -> LDS images complete

        // S^T = K Q^T: s[n][r] = S[q][key = n*16+lg*4+r]
        f32x4 s[4];
        #pragma unroll
        for (int n = 0; n < 4; ++n) {
            f32x4 sa = (f32x4){0.f, 0.f, 0.f, 0.f};
            #pragma unroll
            for (int ks = 0; ks < 2; ++ks) {
                bf16x8 kb_hi = *(const bf16x8*)&sKh[swz(n * 16 + ln, ks * 32 + lg * 8)];
                bf16x8 kb_lo = *(const bf16x8*)&sKl[swz(n * 16 + ln, ks * 32 + lg * 8)];
                sa = MFMA16(kb_hi, qb_hi[ks], sa);
                sa = MFMA16(kb_lo, qb_hi[ks], sa);
                sa = MFMA16(kb_hi, qb_lo[ks], sa);
            }
            s[n] = sa;
        }

        if (kt == qt) {    // causal mask on the diagonal tile
            const int qloc = w * 16 + ln;
            #pragma unroll
            for (int n = 0; n < 4; ++n)
                #pragma unroll
                for (int r = 0; r < 4; ++r)
                    if (n * 16 + lg * 4 + r > qloc) s[n][r] = -INFINITY;
        }

        // Row max: local 16-tree + 2 shfl (lanes ln, ln+16, ln+32, ln+48)
        float t0 = fmaxf(fmaxf(s[0][0], s[0][1]), fmaxf(s[0][2], s[0][3]));
        float t1 = fmaxf(fmaxf(s[1][0], s[1][1]), fmaxf(s[1][2], s[1][3]));
        float t2 = fmaxf(fmaxf(s[2][0], s[2][1]), fmaxf(s[2][2], s[2][3]));
        float t3 = fmaxf(fmaxf(s[3][0], s[3][1]), fmaxf(s[3][2], s[3][3]));
        float t = fmaxf(fmaxf(t0, t1), fmaxf(t2, t3));
        t = fmaxf(t, __shfl_xor(t, 16));
        t = fmaxf(t, __shfl_xor(t, 32));
        const float mn = fmaxf(m, t);
        const float al = __expf(m - mn);   // exp(-inf)=0 on first tile
        m = mn;

        // p = exp(s - m); row sum via local tree + 2 shfl
        float ps = 0.f;
        #pragma unroll
        for (int n = 0; n < 4; ++n)
            #pragma unroll
            for (int r = 0; r < 4; ++r) {
                s[n][r] = __expf(s[n][r] - mn);
                ps += s[n][r];
            }
        ps += __shfl_xor(ps, 16);
        ps += __shfl_xor(ps, 32);
        lsum = lsum * al + ps;
        #pragma unroll
        for (int n = 0; n < 4; ++n) {
            acc[n][0] *= al; acc[n][1] *= al;
            acc[n][2] *= al; acc[n][3] *= al;
        }

        // Pack P into PV B-frags (pure registers): pb[ks][e] = p[2ks+(e>>2)][e&3]
        bf16x8 pb_hi[2], pb_lo[2];
        #pragma unroll
        for (int ks = 0; ks < 2; ++ks)
            #pragma unroll
            for (int e = 0; e < 8; ++e) {
                short hh, ll;
                bsplit(s[2 * ks + (e >> 2)][e & 3], hh, ll);
                pb_hi[ks][e] = hh;
                pb_lo[ks][e] = ll;
            }

        // PV: O^T tile n (d rows n*16..+15); V image already pi-permuted.
        #pragma unroll
        for (int n = 0; n < 4; ++n) {
            #pragma unroll
            for (int ks = 0; ks < 2; ++ks) {
                bf16x8 vb_hi = *(const bf16x8*)&sVh[swz(n * 16 + ln, ks * 32 + lg * 8)];
                bf16x8 vb_lo = *(const bf16x8*)&sVl[swz(n * 16 + ln, ks * 32 + lg * 8)];
                acc[n] = MFMA16(vb_hi, pb_hi[ks], acc[n]);
                acc[n] = MFMA16(vb_lo, pb_hi[ks], acc[n]);
                acc[n] = MFMA16(vb_hi, pb_lo[ks], acc[n]);
            }
        }
    }

    // Epilogue: lane holds O[q][d = n*16+lg*4+r], q = q0+w*16+ln.
    const float inv = 1.f / lsum;
    const int q = q0 + w * 16 + ln;
    const size_t base = ((size_t)(b * L) + q) * D + h * 64;
    #pragma unroll
    for (int n = 0; n < 4; ++n) {
        unsigned h01 = 0, h23 = 0, l01 = 0, l23 = 0;
        #pragma unroll
        for (int r = 0; r < 4; ++r) {
            short hh, ll;
            bsplit(acc[n][r] * inv, hh, ll);
            if (r < 2) {
                h01 |= (unsigned)(u16)hh << (16 * r);
                l01 |= (unsigned)(u16)ll << (16 * r);
            } else {
                h23 |= (unsigned)(u16)hh << (16 * (r - 2));
                l23 |= (unsigned)(u16)ll << (16 * (r - 2));
            }
        }
        *(uint2*)&ctxh[base + n * 16 + lg * 4] = make_uint2(h01, h23);
        *(uint2*)&ctxl[base + n * 16 + lg * 4] = make_uint2(l01, l23);
    }
}

extern "C" void kernel_launch(void* const* d_in, const int* in_sizes, int n_in,
                              void* d_out, int out_size, void* d_ws, size_t ws_size,
                              hipStream_t stream) {
    const float* x     = (const float*)d_in[0];
    const float* W_qkv = (const float*)d_in[1];
    const float* b_qkv = (const float*)d_in[2];
    const float* W_lin = (const float*)d_in[3];
    const float* b_lin = (const float*)d_in[4];
    float* out = (float*)d_out;

    const int M = 8192, D = 1024, D3 = 3072;
    const size_t MB = 1024 * 1024;

    char* ws = (char*)d_ws;
    u16* Qh  = (u16*)(ws + 0 * MB);
    u16* Ql  = (u16*)(ws + 16 * MB);
    u16* Kh  = (u16*)(ws + 32 * MB);
    u16* Kl  = (u16*)(ws + 48 * MB);
    u16* Vth = (u16*)(ws + 64 * MB);
    u16* Vtl = (u16*)(ws + 80 * MB);
    u16* wqh = (u16*)(ws + 96 * MB);    // pre-attn only (6M)
    u16* wql = (u16*)(ws + 102 * MB);   // pre-attn only (6M)
    u16* ctxh = (u16*)(ws + 96 * MB);   // post-attn (16M)
    u16* ctxl = (u16*)(ws + 112 * MB);  // post-attn (16M)
    u16* wlh = (u16*)(ws + 0 * MB);     // post-attn (2M, dead Q region)
    u16* wll = (u16*)(ws + 2 * MB);     // post-attn (2M)

    // 1) W_qkv -> transposed split
    wsplit_t<<<dim3(D3 / 64, D / 64), 256, 0, stream>>>(W_qkv, wqh, wql, D, D3);
    // 2) QKV GEMM, epilogue -> attention-ready Q/K/V^T layouts
    gemm_split<true, true><<<dim3(D3 / 128, M / 128), 256, 0, stream>>>(
        x, nullptr, nullptr, wqh, wql, b_qkv, nullptr,
        Qh, Ql, Kh, Kl, Vth, Vtl, M, D3, D);
    // 3) attention -> ctx hi/lo (clobbers wq region: dead)
    attn_mfma<<<dim3(32, 16, 4), 256, 0, stream>>>(
        Qh, Ql, Kh, Kl, Vth, Vtl, ctxh, ctxl);
    // 4) W_lin -> transposed split (into dead Q region)
    wsplit_t<<<dim3(D / 64, D / 64), 256, 0, stream>>>(W_lin, wlh, wll, D, D);
    // 5) out = ctx @ W_lin + b_lin
    gemm_split<false, false><<<dim3(D / 128, M / 128), 256, 0, stream>>>(
        nullptr, ctxh, ctxl, wlh, wll, b_lin, out,
        nullptr, nullptr, nullptr, nullptr, nullptr, nullptr, M, D, D);
}